// Round 14
// baseline (511.183 us; speedup 1.0000x reference)
//
#include <hip/hip_runtime.h>
#include <stdint.h>

// Problem: B=4096, S=256, F=64, K=16, L=256
//   logits[b,k,f] = sum_s x[b,s,f] * W[f,s,k]   (x NaN->0)
//   idx[b,f] = argmax_k logits[b,k,f]           (first max wins)
//   out[b,f,l] = snippet_list[f, idx[b,f], l]
constexpr int Bn = 4096, Sn = 256, Fn = 64, Kn = 16;

// W[f][s][k] -> Wl[s][kq][f][r]  (float4 view: Wl4[(s*4+kq)*64+f])
__global__ void transpose_w_kernel(const float* __restrict__ W, float* __restrict__ Wl) {
  int t = blockIdx.x * 256 + threadIdx.x;          // t = ((s*4+kq)*64+f)*4+r
  int r = t & 3, f = (t >> 2) & 63, kq = (t >> 8) & 3, s = t >> 10;
  Wl[t] = W[(f * Sn + s) * Kn + kq * 4 + r];
}

// async global->LDS, 16B per lane; LDS dest = wave-uniform base + lane*16
__device__ __forceinline__ void gld_lds16(const float4* g, float4* l) {
  __builtin_amdgcn_global_load_lds(
      (const __attribute__((address_space(1))) uint32_t*)g,
      (__attribute__((address_space(3))) uint32_t*)l, 16, 0, 0);
}

// ---------------- best-known production path (R13, unchanged) --------------
__global__ __launch_bounds__(256, 2) void fused_kernel(
    const float* __restrict__ x, const float4* __restrict__ Wl4,
    const float4* __restrict__ snip4, float4* __restrict__ out4) {
  __shared__ float4 Wbuf[2][2048];   // [parity][(s8*4+kq)*64 + f]  64 KB
  __shared__ int idxs[8][64];        // [b in block][f]              2 KB

  const int tid = threadIdx.x;
  const int lane = tid & 63;            // f
  const int w = tid >> 6;               // 0..3
  const int bbase = blockIdx.x * 8;
  const int b0 = bbase + w * 2;
  const size_t xrow = (size_t)Sn * Fn;
  const float* xb0 = x + (size_t)b0 * xrow + lane;

  float acc[2][16];
#pragma unroll
  for (int j = 0; j < 2; ++j)
#pragma unroll
    for (int k = 0; k < 16; ++k) acc[j][k] = 0.f;

  float xA[8][2], xB[8][2];

#define STAGEW(c, p)                                                         \
  {                                                                          \
    const float4* _src = Wl4 + (size_t)(c) * 2048 + (w * 8) * 64 + lane;     \
    float4* _dst = &Wbuf[p][(w * 8) * 64];                                   \
    _Pragma("unroll") for (int ii = 0; ii < 8; ++ii)                         \
        gld_lds16(_src + ii * 64, _dst + ii * 64);                           \
  }
#define LOADX(c, xn)                                                         \
  {                                                                          \
    _Pragma("unroll") for (int s8 = 0; s8 < 8; ++s8)                         \
        _Pragma("unroll") for (int j = 0; j < 2; ++j)                        \
            xn[s8][j] = xb0[(size_t)j * xrow + (size_t)((c) * 8 + s8) * Fn]; \
  }
#define COMPUTE(p, xn)                                                       \
  {                                                                          \
    _Pragma("unroll") for (int s8 = 0; s8 < 8; ++s8) {                       \
      float4 wq[4];                                                          \
      _Pragma("unroll") for (int kq = 0; kq < 4; ++kq)                       \
          wq[kq] = Wbuf[p][(s8 * 4 + kq) * 64 + lane];                       \
      float xv[2];                                                           \
      _Pragma("unroll") for (int j = 0; j < 2; ++j) {                        \
        float v = xn[s8][j];                                                 \
        xv[j] = (v == v) ? v : 0.f;                                          \
      }                                                                      \
      float wv[16];                                                          \
      _Pragma("unroll") for (int kq = 0; kq < 4; ++kq) {                     \
        wv[4 * kq + 0] = wq[kq].x; wv[4 * kq + 1] = wq[kq].y;                \
        wv[4 * kq + 2] = wq[kq].z; wv[4 * kq + 3] = wq[kq].w;                \
      }                                                                      \
      _Pragma("unroll") for (int j = 0; j < 2; ++j)                          \
          _Pragma("unroll") for (int k = 0; k < 16; ++k)                     \
              acc[j][k] = fmaf(xv[j], wv[k], acc[j][k]);                     \
    }                                                                        \
  }

  STAGEW(0, 0);
  LOADX(0, xA);
  __syncthreads();

  for (int cc = 0; cc < 32; cc += 2) {
    STAGEW(cc + 1, 1);
    LOADX(cc + 1, xB);
    COMPUTE(0, xA);
    __syncthreads();
    if (cc + 2 < 32) {
      STAGEW(cc + 2, 0);
      LOADX(cc + 2, xA);
    }
    COMPUTE(1, xB);
    __syncthreads();
  }

#pragma unroll
  for (int j = 0; j < 2; ++j) {
    float bv = acc[j][0];
    int bk = 0;
#pragma unroll
    for (int k = 1; k < 16; ++k)
      if (acc[j][k] > bv) { bv = acc[j][k]; bk = k; }
    idxs[w * 2 + j][lane] = bk;
  }
  __syncthreads();

#pragma unroll 4
  for (int it = 0; it < 128; ++it) {
    int r = (it << 2) | w;
    int bi = r >> 6, f = r & 63;
    int kk = idxs[bi][f];
    float4 v = snip4[(size_t)((f * Kn + kk) << 6) + lane];
    out4[((size_t)(bbase + bi) * Fn + f) * 64 + lane] = v;
  }
#undef STAGEW
#undef LOADX
#undef COMPUTE
}

// ---------------- ablation probes (write to d_ws sink, not d_out) ----------
// MODE 0 = full loop; MODE 1 = noW (x loads + FMA only); MODE 2 = noX
// (W stage + ds_read + FMA only). REPS scales duration so probes clear the
// ~155us fill-dispatch floor of the profiler's top-5 table.
template <int MODE, int REPS>
__global__ __launch_bounds__(256, 2) void abl_kernel(
    const float* __restrict__ x, const float4* __restrict__ Wl4,
    float* __restrict__ sink) {
  __shared__ float4 Wbuf[2][2048];   // keep 64 KB resident in ALL modes

  const int tid = threadIdx.x;
  const int lane = tid & 63;
  const int w = tid >> 6;
  const int b0 = blockIdx.x * 8 + w * 2;
  const size_t xrow = (size_t)Sn * Fn;
  const float* xb0 = x + (size_t)b0 * xrow + lane;

  // pin LDS allocation even when MODE==1 never stages
  Wbuf[0][tid & 2047].x = (float)tid;
  __syncthreads();

  float acc[2][16];
#pragma unroll
  for (int j = 0; j < 2; ++j)
#pragma unroll
    for (int k = 0; k < 16; ++k) acc[j][k] = 0.f;

  float xA[8][2], xB[8][2];

#define STAGEW_A(c, p)                                                       \
  if (MODE != 1) {                                                           \
    const float4* _src = Wl4 + (size_t)(c) * 2048 + (w * 8) * 64 + lane;     \
    float4* _dst = &Wbuf[p][(w * 8) * 64];                                   \
    _Pragma("unroll") for (int ii = 0; ii < 8; ++ii)                         \
        gld_lds16(_src + ii * 64, _dst + ii * 64);                           \
  }
#define LOADX_A(c, xn)                                                       \
  if (MODE != 2) {                                                           \
    _Pragma("unroll") for (int s8 = 0; s8 < 8; ++s8)                         \
        _Pragma("unroll") for (int j = 0; j < 2; ++j)                        \
            xn[s8][j] = xb0[(size_t)j * xrow + (size_t)((c) * 8 + s8) * Fn]; \
  }
#define COMPUTE_A(p, xn)                                                     \
  {                                                                          \
    _Pragma("unroll") for (int s8 = 0; s8 < 8; ++s8) {                       \
      float wv[16];                                                          \
      if (MODE == 1) {                                                       \
        float base = (float)(s8 + 1);  /* s8-dep: blocks reassociation */    \
        _Pragma("unroll") for (int k = 0; k < 16; ++k)                       \
            wv[k] = base * (0.03125f * (float)(k + 1));                      \
      } else {                                                               \
        float4 wq[4];                                                        \
        _Pragma("unroll") for (int kq = 0; kq < 4; ++kq)                     \
            wq[kq] = Wbuf[p][(s8 * 4 + kq) * 64 + lane];                     \
        _Pragma("unroll") for (int kq = 0; kq < 4; ++kq) {                   \
          wv[4 * kq + 0] = wq[kq].x; wv[4 * kq + 1] = wq[kq].y;              \
          wv[4 * kq + 2] = wq[kq].z; wv[4 * kq + 3] = wq[kq].w;              \
        }                                                                    \
      }                                                                      \
      float xv[2];                                                           \
      if (MODE == 2) {                                                       \
        xv[0] = 1.0f; xv[1] = 0.5f;                                          \
      } else {                                                               \
        _Pragma("unroll") for (int j = 0; j < 2; ++j) {                      \
          float v = xn[s8][j];                                               \
          xv[j] = (v == v) ? v : 0.f;                                        \
        }                                                                    \
      }                                                                      \
      _Pragma("unroll") for (int j = 0; j < 2; ++j)                          \
          _Pragma("unroll") for (int k = 0; k < 16; ++k)                     \
              acc[j][k] = fmaf(xv[j], wv[k], acc[j][k]);                     \
    }                                                                        \
  }

  for (int rep = 0; rep < REPS; ++rep) {
    STAGEW_A(0, 0);
    LOADX_A(0, xA);
    __syncthreads();
    for (int cc = 0; cc < 32; cc += 2) {
      STAGEW_A(cc + 1, 1);
      LOADX_A(cc + 1, xB);
      COMPUTE_A(0, xA);
      __syncthreads();
      if (cc + 2 < 32) {
        STAGEW_A(cc + 2, 0);
        LOADX_A(cc + 2, xA);
      }
      COMPUTE_A(1, xB);
      __syncthreads();
    }
  }

  float ssum = 0.f;
#pragma unroll
  for (int j = 0; j < 2; ++j)
#pragma unroll
    for (int k = 0; k < 16; ++k) ssum += acc[j][k];
  sink[blockIdx.x * 256 + tid] = ssum;   // real use: no DCE (rule #17)
#undef STAGEW_A
#undef LOADX_A
#undef COMPUTE_A
}

// Fallback (ws too small): R5's verified fused kernel, direct W reads.
__global__ __launch_bounds__(256, 2) void fused_fallback(
    const float* __restrict__ x, const float* __restrict__ Wsrc,
    const float4* __restrict__ snip4, float4* __restrict__ out4) {
  __shared__ int idxs[8][64];
  const int tid = threadIdx.x;
  const int lane = tid & 63;
  const int w = tid >> 6;
  const int bbase = blockIdx.x * 8;
  const int b0 = bbase + w * 2;
  const size_t xrow = (size_t)Sn * Fn;

  float acc0[16], acc1[16];
#pragma unroll
  for (int k = 0; k < 16; ++k) { acc0[k] = 0.f; acc1[k] = 0.f; }
  const float* pc0 = x + (size_t)b0 * xrow + lane;
  const float* pc1 = pc0 + xrow;
  float xc0[8], xc1[8], xn0[8], xn1[8];
#pragma unroll
  for (int j = 0; j < 8; ++j) { xn0[j] = pc0[j * 64]; xn1[j] = pc1[j * 64]; }
  for (int c = 0; c < 32; ++c) {
#pragma unroll
    for (int j = 0; j < 8; ++j) {
      float v0 = xn0[j], v1 = xn1[j];
      xc0[j] = (v0 == v0) ? v0 : 0.f;
      xc1[j] = (v1 == v1) ? v1 : 0.f;
    }
    if (c < 31) {
      pc0 += 512; pc1 += 512;
#pragma unroll
      for (int j = 0; j < 8; ++j) { xn0[j] = pc0[j * 64]; xn1[j] = pc1[j * 64]; }
    }
#pragma unroll
    for (int s8 = 0; s8 < 8; ++s8) {
      const int s = c * 8 + s8;
      float wv[16];
      const float4* wq = reinterpret_cast<const float4*>(Wsrc) + ((size_t)(lane * Sn + s) << 2);
#pragma unroll
      for (int jj = 0; jj < 4; ++jj) {
        float4 q = wq[jj];
        wv[4 * jj + 0] = q.x; wv[4 * jj + 1] = q.y; wv[4 * jj + 2] = q.z; wv[4 * jj + 3] = q.w;
      }
#pragma unroll
      for (int k = 0; k < 16; ++k) {
        acc0[k] = fmaf(xc0[s8], wv[k], acc0[k]);
        acc1[k] = fmaf(xc1[s8], wv[k], acc1[k]);
      }
    }
  }
  {
    float bv0 = acc0[0], bv1 = acc1[0];
    int bk0 = 0, bk1 = 0;
#pragma unroll
    for (int k = 1; k < 16; ++k) {
      if (acc0[k] > bv0) { bv0 = acc0[k]; bk0 = k; }
      if (acc1[k] > bv1) { bv1 = acc1[k]; bk1 = k; }
    }
    idxs[w * 2 + 0][lane] = bk0;
    idxs[w * 2 + 1][lane] = bk1;
  }
  __syncthreads();
#pragma unroll 4
  for (int it = 0; it < 128; ++it) {
    int r = (it << 2) | w;
    int bi = r >> 6, f = r & 63;
    int kk = idxs[bi][f];
    float4 v = snip4[(size_t)((f * Kn + kk) << 6) + lane];
    out4[((size_t)(bbase + bi) * Fn + f) * 64 + lane] = v;
  }
}

extern "C" void kernel_launch(void* const* d_in, const int* in_sizes, int n_in,
                              void* d_out, int out_size, void* d_ws, size_t ws_size,
                              hipStream_t stream) {
  const float* x = (const float*)d_in[0];
  const float* W = (const float*)d_in[1];
  const float* snip = (const float*)d_in[2];
  float4* out4 = (float4*)d_out;
  const float4* snip4 = (const float4*)snip;

  const size_t wl_bytes = (size_t)Sn * Fn * Kn * sizeof(float);   // 1 MB
  const size_t sink_bytes = (size_t)512 * 256 * sizeof(float);    // 512 KB
  if (ws_size >= wl_bytes + sink_bytes) {
    float* Wl = (float*)d_ws;
    float* sink = (float*)((char*)d_ws + wl_bytes);
    transpose_w_kernel<<<(Sn * Fn * Kn) / 256, 256, 0, stream>>>(W, Wl);
    fused_kernel<<<Bn / 8, 256, 0, stream>>>(x, (const float4*)Wl, snip4, out4);
    // --- ablation probes (recon round: inflate dur_us by design) ---
    abl_kernel<0, 2><<<Bn / 8, 256, 0, stream>>>(x, (const float4*)Wl, sink);
    abl_kernel<2, 2><<<Bn / 8, 256, 0, stream>>>(x, (const float4*)Wl, sink);
    abl_kernel<1, 4><<<Bn / 8, 256, 0, stream>>>(x, (const float4*)Wl, sink);
  } else {
    fused_fallback<<<Bn / 8, 256, 0, stream>>>(x, W, snip4, out4);
  }
}

// Round 15
// 146.092 us; speedup vs baseline: 3.4991x; 3.4991x over previous
//
#include <hip/hip_runtime.h>
#include <stdint.h>

// Problem: B=4096, S=256, F=64, K=16, L=256
//   logits[b,k,f] = sum_s x[b,s,f] * W[f,s,k]   (x NaN->0)
//   idx[b,f] = argmax_k logits[b,k,f]           (first max wins)
//   out[b,f,l] = snippet_list[f, idx[b,f], l]
constexpr int Bn = 4096, Sn = 256, Fn = 64, Kn = 16;

// W[f][s][k] -> Wl[s][kq][f][r]  (float4 view: Wl4[(s*4+kq)*64+f])
__global__ void transpose_w_kernel(const float* __restrict__ W, float* __restrict__ Wl) {
  int t = blockIdx.x * 256 + threadIdx.x;          // t = ((s*4+kq)*64+f)*4+r
  int r = t & 3, f = (t >> 2) & 63, kq = (t >> 8) & 3, s = t >> 10;
  Wl[t] = W[(f * Sn + s) * Kn + kq * 4 + r];
}

// async global->LDS, 16B per lane; LDS dest = wave-uniform base + lane*16
__device__ __forceinline__ void gld_lds16(const float4* g, float4* l) {
  __builtin_amdgcn_global_load_lds(
      (const __attribute__((address_space(1))) uint32_t*)g,
      (__attribute__((address_space(3))) uint32_t*)l, 16, 0, 0);
}

// FUSED gemm+argmax+gather. R13 structure with 4-s W chunks:
// LDS = 32 KB dbuf + 2 KB idx -> __launch_bounds__(256,4) -> 4 blocks/CU
// (16 waves/CU, 4/SIMD): independent blocks cover each other's
// stage/barrier latency windows (R14 ablation: x-alone and W-alone are
// both fast; the combination stalls at 2 blocks/CU).
// Grid 512 x 256 threads (4 waves). Wave w: batches blk*8+w*2+{0,1},
// full s. lane = f. W staged per 4-s chunk (16 KB) via global_load_lds,
// double-buffered; x register-prefetched one chunk ahead (8 floats/buf).
__global__ __launch_bounds__(256, 4) void fused_kernel(
    const float* __restrict__ x, const float4* __restrict__ Wl4,
    const float4* __restrict__ snip4, float4* __restrict__ out4) {
  __shared__ float4 Wbuf[2][1024];   // [parity][(s4*4+kq)*64 + f]  32 KB
  __shared__ int idxs[8][64];        // [b in block][f]              2 KB

  const int tid = threadIdx.x;
  const int lane = tid & 63;            // f
  const int w = tid >> 6;               // 0..3
  const int bbase = blockIdx.x * 8;
  const int b0 = bbase + w * 2;
  const size_t xrow = (size_t)Sn * Fn;
  const float* xb0 = x + (size_t)b0 * xrow + lane;

  float acc[2][16];
#pragma unroll
  for (int j = 0; j < 2; ++j)
#pragma unroll
    for (int k = 0; k < 16; ++k) acc[j][k] = 0.f;

  float xA[4][2], xB[4][2];

// stage W chunk c (4 s-rows = 1024 float4 = 16 KB) into Wbuf[p];
// wave w stages s-row (c*4 + w) = 256 float4 = 4 x 1KB gld_lds
#define STAGEW(c, p)                                                         \
  {                                                                          \
    const float4* _src = Wl4 + (size_t)(c) * 1024 + w * 256 + lane;          \
    float4* _dst = &Wbuf[p][w * 256];                                        \
    _Pragma("unroll") for (int ii = 0; ii < 4; ++ii)                         \
        gld_lds16(_src + ii * 64, _dst + ii * 64);                           \
  }

// load x chunk c (4 s x 2 b, 256 B coalesced wave-loads) into reg buffer
#define LOADX(c, xn)                                                         \
  {                                                                          \
    _Pragma("unroll") for (int s4 = 0; s4 < 4; ++s4)                         \
        _Pragma("unroll") for (int j = 0; j < 2; ++j)                        \
            xn[s4][j] = xb0[(size_t)j * xrow + (size_t)((c) * 4 + s4) * Fn]; \
  }

// compute chunk from Wbuf[p] and reg buffer xn (NaN->0 applied at use)
#define COMPUTE(p, xn)                                                       \
  {                                                                          \
    _Pragma("unroll") for (int s4 = 0; s4 < 4; ++s4) {                       \
      float4 wq[4];                                                          \
      _Pragma("unroll") for (int kq = 0; kq < 4; ++kq)                       \
          wq[kq] = Wbuf[p][(s4 * 4 + kq) * 64 + lane];                       \
      float xv[2];                                                           \
      _Pragma("unroll") for (int j = 0; j < 2; ++j) {                        \
        float v = xn[s4][j];                                                 \
        xv[j] = (v == v) ? v : 0.f;                                          \
      }                                                                      \
      _Pragma("unroll") for (int j = 0; j < 2; ++j)                          \
          _Pragma("unroll") for (int kq = 0; kq < 4; ++kq) {                 \
        acc[j][4 * kq + 0] = fmaf(xv[j], wq[kq].x, acc[j][4 * kq + 0]);      \
        acc[j][4 * kq + 1] = fmaf(xv[j], wq[kq].y, acc[j][4 * kq + 1]);      \
        acc[j][4 * kq + 2] = fmaf(xv[j], wq[kq].z, acc[j][4 * kq + 2]);      \
        acc[j][4 * kq + 3] = fmaf(xv[j], wq[kq].w, acc[j][4 * kq + 3]);      \
      }                                                                      \
    }                                                                        \
  }

  // prologue
  STAGEW(0, 0);
  LOADX(0, xA);
  __syncthreads();

  // 2-phase: stage next chunk before computing current; 1 barrier/chunk.
  // 64 chunks of 4 s.
  for (int cc = 0; cc < 64; cc += 2) {
    STAGEW(cc + 1, 1);
    LOADX(cc + 1, xB);
    COMPUTE(0, xA);
    __syncthreads();
    if (cc + 2 < 64) {
      STAGEW(cc + 2, 0);
      LOADX(cc + 2, xA);
    }
    COMPUTE(1, xB);
    __syncthreads();
  }

  // per-thread argmax (strict >, ascending k: first max wins) -> LDS
#pragma unroll
  for (int j = 0; j < 2; ++j) {
    float bv = acc[j][0];
    int bk = 0;
#pragma unroll
    for (int k = 1; k < 16; ++k)
      if (acc[j][k] > bv) { bv = acc[j][k]; bk = k; }
    idxs[w * 2 + j][lane] = bk;
  }
  __syncthreads();

  // fused gather: 8 b * 64 f = 512 rows of 1 KB; 4 consecutive rows per
  // round across the 4 waves -> 4 KB contiguous writes, fully coalesced.
#pragma unroll 4
  for (int it = 0; it < 128; ++it) {
    int r = (it << 2) | w;
    int bi = r >> 6, f = r & 63;
    int kk = idxs[bi][f];
    float4 v = snip4[(size_t)((f * Kn + kk) << 6) + lane];
    out4[((size_t)(bbase + bi) * Fn + f) * 64 + lane] = v;
  }
#undef STAGEW
#undef LOADX
#undef COMPUTE
}

// Fallback (ws too small): R5's verified fused kernel, direct W reads.
__global__ __launch_bounds__(256, 2) void fused_fallback(
    const float* __restrict__ x, const float* __restrict__ Wsrc,
    const float4* __restrict__ snip4, float4* __restrict__ out4) {
  __shared__ int idxs[8][64];
  const int tid = threadIdx.x;
  const int lane = tid & 63;
  const int w = tid >> 6;
  const int bbase = blockIdx.x * 8;
  const int b0 = bbase + w * 2;
  const size_t xrow = (size_t)Sn * Fn;

  float acc0[16], acc1[16];
#pragma unroll
  for (int k = 0; k < 16; ++k) { acc0[k] = 0.f; acc1[k] = 0.f; }
  const float* pc0 = x + (size_t)b0 * xrow + lane;
  const float* pc1 = pc0 + xrow;
  float xc0[8], xc1[8], xn0[8], xn1[8];
#pragma unroll
  for (int j = 0; j < 8; ++j) { xn0[j] = pc0[j * 64]; xn1[j] = pc1[j * 64]; }
  for (int c = 0; c < 32; ++c) {
#pragma unroll
    for (int j = 0; j < 8; ++j) {
      float v0 = xn0[j], v1 = xn1[j];
      xc0[j] = (v0 == v0) ? v0 : 0.f;
      xc1[j] = (v1 == v1) ? v1 : 0.f;
    }
    if (c < 31) {
      pc0 += 512; pc1 += 512;
#pragma unroll
      for (int j = 0; j < 8; ++j) { xn0[j] = pc0[j * 64]; xn1[j] = pc1[j * 64]; }
    }
#pragma unroll
    for (int s8 = 0; s8 < 8; ++s8) {
      const int s = c * 8 + s8;
      float wv[16];
      const float4* wq = reinterpret_cast<const float4*>(Wsrc) + ((size_t)(lane * Sn + s) << 2);
#pragma unroll
      for (int jj = 0; jj < 4; ++jj) {
        float4 q = wq[jj];
        wv[4 * jj + 0] = q.x; wv[4 * jj + 1] = q.y; wv[4 * jj + 2] = q.z; wv[4 * jj + 3] = q.w;
      }
#pragma unroll
      for (int k = 0; k < 16; ++k) {
        acc0[k] = fmaf(xc0[s8], wv[k], acc0[k]);
        acc1[k] = fmaf(xc1[s8], wv[k], acc1[k]);
      }
    }
  }
  {
    float bv0 = acc0[0], bv1 = acc1[0];
    int bk0 = 0, bk1 = 0;
#pragma unroll
    for (int k = 1; k < 16; ++k) {
      if (acc0[k] > bv0) { bv0 = acc0[k]; bk0 = k; }
      if (acc1[k] > bv1) { bv1 = acc1[k]; bk1 = k; }
    }
    idxs[w * 2 + 0][lane] = bk0;
    idxs[w * 2 + 1][lane] = bk1;
  }
  __syncthreads();
#pragma unroll 4
  for (int it = 0; it < 128; ++it) {
    int r = (it << 2) | w;
    int bi = r >> 6, f = r & 63;
    int kk = idxs[bi][f];
    float4 v = snip4[(size_t)((f * Kn + kk) << 6) + lane];
    out4[((size_t)(bbase + bi) * Fn + f) * 64 + lane] = v;
  }
}

extern "C" void kernel_launch(void* const* d_in, const int* in_sizes, int n_in,
                              void* d_out, int out_size, void* d_ws, size_t ws_size,
                              hipStream_t stream) {
  const float* x = (const float*)d_in[0];
  const float* W = (const float*)d_in[1];
  const float* snip = (const float*)d_in[2];
  float4* out4 = (float4*)d_out;
  const float4* snip4 = (const float4*)snip;

  const size_t wl_bytes = (size_t)Sn * Fn * Kn * sizeof(float);   // 1 MB
  if (ws_size >= wl_bytes) {
    float* Wl = (float*)d_ws;
    transpose_w_kernel<<<(Sn * Fn * Kn) / 256, 256, 0, stream>>>(W, Wl);
    fused_kernel<<<Bn / 8, 256, 0, stream>>>(x, (const float4*)Wl, snip4, out4);
  } else {
    fused_fallback<<<Bn / 8, 256, 0, stream>>>(x, W, snip4, out4);
  }
}

// Round 16
// 129.479 us; speedup vs baseline: 3.9480x; 1.1283x over previous
//
#include <hip/hip_runtime.h>
#include <stdint.h>

// Problem: B=4096, S=256, F=64, K=16, L=256
//   logits[b,k,f] = sum_s x[b,s,f] * W[f,s,k]   (x NaN->0)
//   idx[b,f] = argmax_k logits[b,k,f]           (first max wins)
//   out[b,f,l] = snippet_list[f, idx[b,f], l]
constexpr int Bn = 4096, Sn = 256, Fn = 64, Kn = 16;

// W[f][s][k] -> Wl[s][kq][f][r]  (float4 view: Wl4[(s*4+kq)*64+f])
__global__ void transpose_w_kernel(const float* __restrict__ W, float* __restrict__ Wl) {
  int t = blockIdx.x * 256 + threadIdx.x;          // t = ((s*4+kq)*64+f)*4+r
  int r = t & 3, f = (t >> 2) & 63, kq = (t >> 8) & 3, s = t >> 10;
  Wl[t] = W[(f * Sn + s) * Kn + kq * 4 + r];
}

// async global->LDS, 16B per lane; LDS dest = wave-uniform base + lane*16
__device__ __forceinline__ void gld_lds16(const float4* g, float4* l) {
  __builtin_amdgcn_global_load_lds(
      (const __attribute__((address_space(1))) uint32_t*)g,
      (__attribute__((address_space(3))) uint32_t*)l, 16, 0, 0);
}

// FUSED gemm+argmax+gather, bt=4 (double W-reuse per LDS read vs R13).
// Grid 512 x 256 threads (4 waves). wave w: q=w&1 (batch quad),
// h=w>>1 (s-half). Wave (q,h): batches blk*8+q*4+{0..3},
// s in [h*128, h*128+128) as 32 chunks of 4 s. lane = f.
// Per-half W chunks (16 KB) double-buffered via global_load_lds
// (64 KB LDS total); the 2 quad-waves of a half co-stage (8 gld_lds each).
// Per-CU ds_read_b128 halves vs R13 (each read feeds 4 batches' FMAs).
// x register-prefetched one chunk ahead (16 loads/chunk, same as R13).
// Epilogue: cross-half reduce in aliased Wbuf, argmax, fused gather.
__global__ __launch_bounds__(256, 2) void fused_kernel(
    const float* __restrict__ x, const float4* __restrict__ Wl4,
    const float4* __restrict__ snip4, float4* __restrict__ out4) {
  __shared__ float4 Wbuf[2][2][1024];  // [half][parity][(s4*4+kq)*64+f] 64 KB
  __shared__ int idxs[8][64];          // [q*4+j][f]                     2 KB

  const int tid = threadIdx.x;
  const int lane = tid & 63;            // f
  const int w = tid >> 6;               // 0..3
  const int q = w & 1;                  // batch quad
  const int h = w >> 1;                 // s-half
  const int bbase = blockIdx.x * 8;
  const int b0 = bbase + q * 4;
  const size_t xrow = (size_t)Sn * Fn;
  const float* xb0 = x + (size_t)b0 * xrow + (size_t)(h * 128) * Fn + lane;
  const float4* wsrc0 = Wl4 + (size_t)(h * 128) * 256;  // this half's W rows

  float acc[4][16];
#pragma unroll
  for (int j = 0; j < 4; ++j)
#pragma unroll
    for (int k = 0; k < 16; ++k) acc[j][k] = 0.f;

  float xA[4][4], xB[4][4];

// stage W chunk c (4 s-rows = 1024 float4 = 16 KB) into Wbuf[h][p];
// wave (q,h) stages rows {c*4+2q, c*4+2q+1} = 512 float4 = 8 x 1KB
#define STAGEW(c, p)                                                         \
  {                                                                          \
    const float4* _src = wsrc0 + (size_t)((c) * 4 + 2 * q) * 256 + lane;     \
    float4* _dst = &Wbuf[h][p][(2 * q) * 256];                               \
    _Pragma("unroll") for (int ii = 0; ii < 8; ++ii)                         \
        gld_lds16(_src + ii * 64, _dst + ii * 64);                           \
  }

// load x chunk c (4 s x 4 b, 256 B coalesced wave-loads) into reg buffer
#define LOADX(c, xn)                                                         \
  {                                                                          \
    _Pragma("unroll") for (int s4 = 0; s4 < 4; ++s4)                         \
        _Pragma("unroll") for (int j = 0; j < 4; ++j)                        \
            xn[s4][j] = xb0[(size_t)j * xrow + (size_t)((c) * 4 + s4) * Fn]; \
  }

// compute chunk from Wbuf[h][p] and reg buffer xn (NaN->0 applied at use)
#define COMPUTE(p, xn)                                                       \
  {                                                                          \
    _Pragma("unroll") for (int s4 = 0; s4 < 4; ++s4) {                       \
      float4 wq[4];                                                          \
      _Pragma("unroll") for (int kq = 0; kq < 4; ++kq)                       \
          wq[kq] = Wbuf[h][p][(s4 * 4 + kq) * 64 + lane];                    \
      float xv[4];                                                           \
      _Pragma("unroll") for (int j = 0; j < 4; ++j) {                        \
        float v = xn[s4][j];                                                 \
        xv[j] = (v == v) ? v : 0.f;                                          \
      }                                                                      \
      _Pragma("unroll") for (int j = 0; j < 4; ++j)                          \
          _Pragma("unroll") for (int kq = 0; kq < 4; ++kq) {                 \
        acc[j][4 * kq + 0] = fmaf(xv[j], wq[kq].x, acc[j][4 * kq + 0]);      \
        acc[j][4 * kq + 1] = fmaf(xv[j], wq[kq].y, acc[j][4 * kq + 1]);      \
        acc[j][4 * kq + 2] = fmaf(xv[j], wq[kq].z, acc[j][4 * kq + 2]);      \
        acc[j][4 * kq + 3] = fmaf(xv[j], wq[kq].w, acc[j][4 * kq + 3]);      \
      }                                                                      \
    }                                                                        \
  }

  // prologue
  STAGEW(0, 0);
  LOADX(0, xA);
  __syncthreads();

  // 2-phase: stage next chunk before computing current; 1 barrier/chunk.
  // 32 chunks of 4 s per half.
  for (int cc = 0; cc < 32; cc += 2) {
    STAGEW(cc + 1, 1);
    LOADX(cc + 1, xB);
    COMPUTE(0, xA);
    __syncthreads();
    if (cc + 2 < 32) {
      STAGEW(cc + 2, 0);
      LOADX(cc + 2, xA);
    }
    COMPUTE(1, xB);
    __syncthreads();
  }

  // cross-half reduce in aliased Wbuf (32 KB needed of 64), then argmax
  float* red = reinterpret_cast<float*>(&Wbuf[0][0][0]);
  if (h == 1) {
#pragma unroll
    for (int j = 0; j < 4; ++j)
#pragma unroll
      for (int k = 0; k < 16; ++k)
        red[((q * 4 + j) * 16 + k) * 64 + lane] = acc[j][k];
  }
  __syncthreads();
  if (h == 0) {
#pragma unroll
    for (int j = 0; j < 4; ++j) {
#pragma unroll
      for (int k = 0; k < 16; ++k)
        acc[j][k] += red[((q * 4 + j) * 16 + k) * 64 + lane];
      float bv = acc[j][0];
      int bk = 0;
#pragma unroll
      for (int k = 1; k < 16; ++k)
        if (acc[j][k] > bv) { bv = acc[j][k]; bk = k; }  // first max wins
      idxs[q * 4 + j][lane] = bk;
    }
  }
  __syncthreads();

  // fused gather: 8 b * 64 f = 512 rows of 1 KB; 4 consecutive rows per
  // round across the 4 waves -> 4 KB contiguous writes, fully coalesced.
#pragma unroll 4
  for (int it = 0; it < 128; ++it) {
    int r = (it << 2) | w;
    int bi = r >> 6, f = r & 63;
    int kk = idxs[bi][f];
    float4 v = snip4[(size_t)((f * Kn + kk) << 6) + lane];
    out4[((size_t)(bbase + bi) * Fn + f) * 64 + lane] = v;
  }
#undef STAGEW
#undef LOADX
#undef COMPUTE
}

// Fallback (ws too small): R5's verified fused kernel, direct W reads.
__global__ __launch_bounds__(256, 2) void fused_fallback(
    const float* __restrict__ x, const float* __restrict__ Wsrc,
    const float4* __restrict__ snip4, float4* __restrict__ out4) {
  __shared__ int idxs[8][64];
  const int tid = threadIdx.x;
  const int lane = tid & 63;
  const int w = tid >> 6;
  const int bbase = blockIdx.x * 8;
  const int b0 = bbase + w * 2;
  const size_t xrow = (size_t)Sn * Fn;

  float acc0[16], acc1[16];
#pragma unroll
  for (int k = 0; k < 16; ++k) { acc0[k] = 0.f; acc1[k] = 0.f; }
  const float* pc0 = x + (size_t)b0 * xrow + lane;
  const float* pc1 = pc0 + xrow;
  float xc0[8], xc1[8], xn0[8], xn1[8];
#pragma unroll
  for (int j = 0; j < 8; ++j) { xn0[j] = pc0[j * 64]; xn1[j] = pc1[j * 64]; }
  for (int c = 0; c < 32; ++c) {
#pragma unroll
    for (int j = 0; j < 8; ++j) {
      float v0 = xn0[j], v1 = xn1[j];
      xc0[j] = (v0 == v0) ? v0 : 0.f;
      xc1[j] = (v1 == v1) ? v1 : 0.f;
    }
    if (c < 31) {
      pc0 += 512; pc1 += 512;
#pragma unroll
      for (int j = 0; j < 8; ++j) { xn0[j] = pc0[j * 64]; xn1[j] = pc1[j * 64]; }
    }
#pragma unroll
    for (int s8 = 0; s8 < 8; ++s8) {
      const int s = c * 8 + s8;
      float wv[16];
      const float4* wq = reinterpret_cast<const float4*>(Wsrc) + ((size_t)(lane * Sn + s) << 2);
#pragma unroll
      for (int jj = 0; jj < 4; ++jj) {
        float4 qv = wq[jj];
        wv[4 * jj + 0] = qv.x; wv[4 * jj + 1] = qv.y; wv[4 * jj + 2] = qv.z; wv[4 * jj + 3] = qv.w;
      }
#pragma unroll
      for (int k = 0; k < 16; ++k) {
        acc0[k] = fmaf(xc0[s8], wv[k], acc0[k]);
        acc1[k] = fmaf(xc1[s8], wv[k], acc1[k]);
      }
    }
  }
  {
    float bv0 = acc0[0], bv1 = acc1[0];
    int bk0 = 0, bk1 = 0;
#pragma unroll
    for (int k = 1; k < 16; ++k) {
      if (acc0[k] > bv0) { bv0 = acc0[k]; bk0 = k; }
      if (acc1[k] > bv1) { bv1 = acc1[k]; bk1 = k; }
    }
    idxs[w * 2 + 0][lane] = bk0;
    idxs[w * 2 + 1][lane] = bk1;
  }
  __syncthreads();
#pragma unroll 4
  for (int it = 0; it < 128; ++it) {
    int r = (it << 2) | w;
    int bi = r >> 6, f = r & 63;
    int kk = idxs[bi][f];
    float4 v = snip4[(size_t)((f * Kn + kk) << 6) + lane];
    out4[((size_t)(bbase + bi) * Fn + f) * 64 + lane] = v;
  }
}

extern "C" void kernel_launch(void* const* d_in, const int* in_sizes, int n_in,
                              void* d_out, int out_size, void* d_ws, size_t ws_size,
                              hipStream_t stream) {
  const float* x = (const float*)d_in[0];
  const float* W = (const float*)d_in[1];
  const float* snip = (const float*)d_in[2];
  float4* out4 = (float4*)d_out;
  const float4* snip4 = (const float4*)snip;

  const size_t wl_bytes = (size_t)Sn * Fn * Kn * sizeof(float);   // 1 MB
  if (ws_size >= wl_bytes) {
    float* Wl = (float*)d_ws;
    transpose_w_kernel<<<(Sn * Fn * Kn) / 256, 256, 0, stream>>>(W, Wl);
    fused_kernel<<<Bn / 8, 256, 0, stream>>>(x, (const float4*)Wl, snip4, out4);
  } else {
    fused_fallback<<<Bn / 8, 256, 0, stream>>>(x, W, snip4, out4);
  }
}